// Round 3
// baseline (7735.345 us; speedup 1.0000x reference)
//
#include <hip/hip_runtime.h>
#include <math.h>

// ---------------- problem constants ----------------
#define B_    128
#define T_    64
#define INX   512
#define CTRL  512
#define NN    128
#define MMM   128
#define RR    4
#define LLh   134   // per-read-head instr length (3+MM+S)
#define NOUT  926
#define NOUTP 928   // padded Wk column stride (16B-aligned rows)
#define NTHR  512   // 2 batches/WG

// Mem row stride 129: bank(129n+m)%32 = (n+m)%32 -> conflict-free both axes
#define MSTR  129

struct __align__(16) SM2 {
  float Mem[2][NN][MSTR];     // 132,096 B (persistent per-WG)
  float rw[2][RR][NN];        //   4,096 B
  float ww[2][NN];            //   1,024 B
  float instr[2][NOUTP];      //   7,424 B
  float rv[2][512];           //   4,096 B
  union {                     //  12,288 B
    struct { float out_s[2][512]; float red[256][8]; } c;   // GEMV phases
    struct { float red[2][256]; float wi[2][NN]; float invn[2][MMM]; float scal[2][8]; } d;
  } u;
};  // 161,024 B -> 1 WG/CU, 64 WGs (weights L2-resident per XCD)

__device__ __forceinline__ float comp(const float4& v, int i) {
  return i == 0 ? v.x : i == 1 ? v.y : i == 2 ? v.z : v.w;
}

// ---------------- per-half (256-thread) reductions; all 512 threads call together ----
__device__ __forceinline__ float red_sum_half(float v, volatile float* scal4, int tid) {
  #pragma unroll
  for (int m = 32; m >= 1; m >>= 1) v += __shfl_xor(v, m);
  if ((tid & 63) == 0) scal4[(tid >> 6) & 3] = v;
  __syncthreads();
  float r = scal4[0] + scal4[1] + scal4[2] + scal4[3];
  __syncthreads();
  return r;
}
__device__ __forceinline__ float red_max_half(float v, volatile float* scal4, int tid) {
  #pragma unroll
  for (int m = 32; m >= 1; m >>= 1) v = fmaxf(v, __shfl_xor(v, m));
  if ((tid & 63) == 0) scal4[(tid >> 6) & 3] = v;
  __syncthreads();
  float r = fmaxf(fmaxf(scal4[0], scal4[1]), fmaxf(scal4[2], scal4[3]));
  __syncthreads();
  return r;
}

// ---------------- precompute: d_out = X(8192x512) @ Wc[0:512,:] + bc ----------------
__global__ __launch_bounds__(256) void pre_mm(const float* __restrict__ X,
                                              const float* __restrict__ Wc,
                                              const float* __restrict__ bc,
                                              float* __restrict__ out) {
  __shared__ float Xs[16][68];
  __shared__ float Ws[16][64];
  const int wg = blockIdx.x;
  const int r0 = (wg >> 3) * 64, c0 = (wg & 7) * 64;
  const int tid = threadIdx.x;
  const int ti = tid >> 4, tj = tid & 15;
  float acc[4][4] = {};
  for (int kk = 0; kk < 512; kk += 16) {
    __syncthreads();
    for (int e = tid; e < 1024; e += 256) {
      int i = e >> 4, k = e & 15;
      Xs[k][i] = X[(size_t)(r0 + i) * 512 + kk + k];
    }
    for (int e = tid; e < 1024; e += 256) {
      int k = e >> 6, j = e & 63;
      Ws[k][j] = Wc[(size_t)(kk + k) * CTRL + c0 + j];
    }
    __syncthreads();
    #pragma unroll
    for (int k = 0; k < 16; ++k) {
      float a0 = Xs[k][ti*4+0], a1 = Xs[k][ti*4+1], a2 = Xs[k][ti*4+2], a3 = Xs[k][ti*4+3];
      float b0 = Ws[k][tj*4+0], b1 = Ws[k][tj*4+1], b2 = Ws[k][tj*4+2], b3 = Ws[k][tj*4+3];
      acc[0][0]+=a0*b0; acc[0][1]+=a0*b1; acc[0][2]+=a0*b2; acc[0][3]+=a0*b3;
      acc[1][0]+=a1*b0; acc[1][1]+=a1*b1; acc[1][2]+=a1*b2; acc[1][3]+=a1*b3;
      acc[2][0]+=a2*b0; acc[2][1]+=a2*b1; acc[2][2]+=a2*b2; acc[2][3]+=a2*b3;
      acc[3][0]+=a3*b0; acc[3][1]+=a3*b1; acc[3][2]+=a3*b2; acc[3][3]+=a3*b3;
    }
  }
  #pragma unroll
  for (int i = 0; i < 4; ++i) {
    size_t o = (size_t)(r0 + ti*4 + i) * 512 + c0 + tj*4;
    float4 v = { acc[i][0] + bc[c0+tj*4+0], acc[i][1] + bc[c0+tj*4+1],
                 acc[i][2] + bc[c0+tj*4+2], acc[i][3] + bc[c0+tj*4+3] };
    *(float4*)&out[o] = v;
  }
}

// ---------------- pack Wk (stride 926) -> Wkp (stride 928, zero-pad), bk -> bkp ------
__global__ __launch_bounds__(256) void pack_wk(const float* __restrict__ Wk,
                                               const float* __restrict__ bk,
                                               float* __restrict__ Wkp,
                                               float* __restrict__ bkp) {
  const int r = blockIdx.x;   // 512 rows
  for (int c = threadIdx.x; c < NOUTP; c += 256)
    Wkp[(size_t)r * NOUTP + c] = (c < NOUT) ? Wk[(size_t)r * NOUT + c] : 0.f;
  if (r == 0)
    for (int c = threadIdx.x; c < NOUTP; c += 256)
      bkp[c] = (c < NOUT) ? bk[c] : 0.f;
}

// ---------------- persistent per-batch-pair kernel: NO grid sync ----------------
__global__ __launch_bounds__(512) void ntm2(const float* __restrict__ Wc,
                                            const float* __restrict__ Wkp,
                                            const float* __restrict__ bkp,
                                            float* __restrict__ out) {
  __shared__ SM2 sm;
  const int wg = blockIdx.x, tid = threadIdx.x;
  const int b0 = wg * 2;
  const int lt = tid & 255, bb = tid >> 8;   // phase-D: half-local id / batch
  const int jqB = tid & 127, kqB = tid >> 7; // phase-B: 128 col-groups x 4 k-quarters
  const int jqC = tid & 255, kqC = tid >> 8; // phase-C: 256 col-groups x 2 k-halves

  // ---- init state ----
  for (int e = tid; e < 2 * NN * MMM; e += NTHR) {
    int bl = e >> 14, n = (e >> 7) & 127;
    sm.Mem[bl][n][e & 127] = (n == NN / 2) ? 1.0f : 0.0f;
  }
  for (int e = tid; e < 2 * RR * NN; e += NTHR) ((float*)sm.rw)[e] = 0.0f;
  for (int e = tid; e < 2 * NN;      e += NTHR) ((float*)sm.ww)[e] = 0.0f;
  for (int e = tid; e < 2 * 512;     e += NTHR) ((float*)sm.rv)[e] = 0.0f;
  __syncthreads();

  for (int t = 0; t < T_; ++t) {
    // ===== phase B: out[b][t][:] = tanh(pre + rv_b @ Wc2), float4 weights =====
    {
      const int kb = kqB * 128;
      const float* wbase = Wc + (size_t)(INX + kb) * CTRL + 4 * jqB;
      float4 a0 = {0,0,0,0}, a1 = {0,0,0,0};
      float4 w0 = *(const float4*)(wbase + (size_t)0 * CTRL);
      float4 w1 = *(const float4*)(wbase + (size_t)1 * CTRL);
      float4 w2 = *(const float4*)(wbase + (size_t)2 * CTRL);
      float4 w3 = *(const float4*)(wbase + (size_t)3 * CTRL);
      for (int kk = 0; kk < 124; kk += 4) {
        float4 r0 = *(const float4*)&sm.rv[0][kb + kk];
        float4 r1 = *(const float4*)&sm.rv[1][kb + kk];
        float4 n0 = *(const float4*)(wbase + (size_t)(kk+4) * CTRL);
        float4 n1 = *(const float4*)(wbase + (size_t)(kk+5) * CTRL);
        float4 n2 = *(const float4*)(wbase + (size_t)(kk+6) * CTRL);
        float4 n3 = *(const float4*)(wbase + (size_t)(kk+7) * CTRL);
        #pragma unroll
        for (int i = 0; i < 4; ++i) {
          float4 w = i==0?w0: i==1?w1: i==2?w2: w3;
          float e0 = comp(r0, i), e1 = comp(r1, i);
          a0.x += e0*w.x; a0.y += e0*w.y; a0.z += e0*w.z; a0.w += e0*w.w;
          a1.x += e1*w.x; a1.y += e1*w.y; a1.z += e1*w.z; a1.w += e1*w.w;
        }
        w0 = n0; w1 = n1; w2 = n2; w3 = n3;
      }
      { // tail kk = 124
        float4 r0 = *(const float4*)&sm.rv[0][kb + 124];
        float4 r1 = *(const float4*)&sm.rv[1][kb + 124];
        #pragma unroll
        for (int i = 0; i < 4; ++i) {
          float4 w = i==0?w0: i==1?w1: i==2?w2: w3;
          float e0 = comp(r0, i), e1 = comp(r1, i);
          a0.x += e0*w.x; a0.y += e0*w.y; a0.z += e0*w.z; a0.w += e0*w.w;
          a1.x += e1*w.x; a1.y += e1*w.y; a1.z += e1*w.z; a1.w += e1*w.w;
        }
      }
      // kq-reduce: stage A (1+3 -> 0+2), stage B (2 -> 0)
      if (kqB & 1) {
        float* p = sm.u.c.red[(kqB >> 1) * 128 + jqB];
        *(float4*)&p[0] = a0; *(float4*)&p[4] = a1;
      }
      __syncthreads();
      if (!(kqB & 1)) {
        float* p = sm.u.c.red[(kqB >> 1) * 128 + jqB];
        float4 q0 = *(float4*)&p[0], q1 = *(float4*)&p[4];
        a0.x+=q0.x; a0.y+=q0.y; a0.z+=q0.z; a0.w+=q0.w;
        a1.x+=q1.x; a1.y+=q1.y; a1.z+=q1.z; a1.w+=q1.w;
      }
      __syncthreads();
      if (kqB == 2) {
        float* p = sm.u.c.red[jqB];
        *(float4*)&p[0] = a0; *(float4*)&p[4] = a1;
      }
      __syncthreads();
      if (kqB == 0) {
        float* p = sm.u.c.red[jqB];
        float4 q0 = *(float4*)&p[0], q1 = *(float4*)&p[4];
        a0.x+=q0.x; a0.y+=q0.y; a0.z+=q0.z; a0.w+=q0.w;
        a1.x+=q1.x; a1.y+=q1.y; a1.z+=q1.z; a1.w+=q1.w;
        size_t o0 = ((size_t)(b0+0) * T_ + t) * CTRL + 4 * jqB;
        size_t o1 = ((size_t)(b0+1) * T_ + t) * CTRL + 4 * jqB;
        float4 p0 = *(const float4*)&out[o0];
        float4 p1 = *(const float4*)&out[o1];
        float4 v0 = { tanhf(p0.x+a0.x), tanhf(p0.y+a0.y), tanhf(p0.z+a0.z), tanhf(p0.w+a0.w) };
        float4 v1 = { tanhf(p1.x+a1.x), tanhf(p1.y+a1.y), tanhf(p1.z+a1.z), tanhf(p1.w+a1.w) };
        *(float4*)&out[o0] = v0;  *(float4*)&out[o1] = v1;
        *(float4*)&sm.u.c.out_s[0][4*jqB] = v0;
        *(float4*)&sm.u.c.out_s[1][4*jqB] = v1;
      }
    }
    __syncthreads();

    // ===== phase C: instr = out_t @ Wkp + bkp, float4 weights =====
    {
      float4 a0 = {0,0,0,0}, a1 = {0,0,0,0};
      if (jqC < 232) {
        const int kb = kqC * 256;
        const float* wbase = Wkp + (size_t)kb * NOUTP + 4 * jqC;
        float4 w0 = *(const float4*)(wbase + (size_t)0 * NOUTP);
        float4 w1 = *(const float4*)(wbase + (size_t)1 * NOUTP);
        float4 w2 = *(const float4*)(wbase + (size_t)2 * NOUTP);
        float4 w3 = *(const float4*)(wbase + (size_t)3 * NOUTP);
        for (int kk = 0; kk < 252; kk += 4) {
          float4 o0 = *(const float4*)&sm.u.c.out_s[0][kb + kk];
          float4 o1 = *(const float4*)&sm.u.c.out_s[1][kb + kk];
          float4 n0 = *(const float4*)(wbase + (size_t)(kk+4) * NOUTP);
          float4 n1 = *(const float4*)(wbase + (size_t)(kk+5) * NOUTP);
          float4 n2 = *(const float4*)(wbase + (size_t)(kk+6) * NOUTP);
          float4 n3 = *(const float4*)(wbase + (size_t)(kk+7) * NOUTP);
          #pragma unroll
          for (int i = 0; i < 4; ++i) {
            float4 w = i==0?w0: i==1?w1: i==2?w2: w3;
            float e0 = comp(o0, i), e1 = comp(o1, i);
            a0.x += e0*w.x; a0.y += e0*w.y; a0.z += e0*w.z; a0.w += e0*w.w;
            a1.x += e1*w.x; a1.y += e1*w.y; a1.z += e1*w.z; a1.w += e1*w.w;
          }
          w0 = n0; w1 = n1; w2 = n2; w3 = n3;
        }
        { // tail kk = 252
          float4 o0 = *(const float4*)&sm.u.c.out_s[0][kb + 252];
          float4 o1 = *(const float4*)&sm.u.c.out_s[1][kb + 252];
          #pragma unroll
          for (int i = 0; i < 4; ++i) {
            float4 w = i==0?w0: i==1?w1: i==2?w2: w3;
            float e0 = comp(o0, i), e1 = comp(o1, i);
            a0.x += e0*w.x; a0.y += e0*w.y; a0.z += e0*w.z; a0.w += e0*w.w;
            a1.x += e1*w.x; a1.y += e1*w.y; a1.z += e1*w.z; a1.w += e1*w.w;
          }
        }
      }
      if (kqC == 1 && jqC < 232) {
        float* p = sm.u.c.red[jqC];
        *(float4*)&p[0] = a0; *(float4*)&p[4] = a1;
      }
      __syncthreads();
      if (kqC == 0 && jqC < 232) {
        float* p = sm.u.c.red[jqC];
        float4 q0 = *(float4*)&p[0], q1 = *(float4*)&p[4];
        float4 bias = *(const float4*)&bkp[4 * jqC];
        a0.x+=q0.x+bias.x; a0.y+=q0.y+bias.y; a0.z+=q0.z+bias.z; a0.w+=q0.w+bias.w;
        a1.x+=q1.x+bias.x; a1.y+=q1.y+bias.y; a1.z+=q1.z+bias.z; a1.w+=q1.w+bias.w;
        *(float4*)&sm.instr[0][4*jqC] = a0;
        *(float4*)&sm.instr[1][4*jqC] = a1;
      }
    }
    __syncthreads();

    // ===== phase D: heads + Mem update + rv (256 threads per batch) =====
    {
      volatile float* scal4 = sm.u.d.scal[bb];
      {
        int m = lt & 127, h = lt >> 7;
        float p = 0.f;
        #pragma unroll 8
        for (int q = 0; q < 64; ++q) { float v = sm.Mem[bb][h*64+q][m]; p += v*v; }
        sm.u.d.red[bb][lt] = p;
      }
      __syncthreads();
      if (lt < 128) sm.u.d.invn[bb][lt] =
          rsqrtf(fmaxf(sm.u.d.red[bb][lt] + sm.u.d.red[bb][lt+128], 1e-12f));
      __syncthreads();

      for (int hd = 0; hd < 5; ++hd) {
        const int off = (hd < RR) ? hd * LLh : RR * LLh;
        float kv = (lt < 128) ? sm.instr[bb][off + lt] : 0.f;
        float kn2 = red_sum_half(kv * kv, scal4, tid);
        float invk = rsqrtf(fmaxf(kn2, 1e-12f));
        float beta = expf(sm.instr[bb][off + 128]);
        float gg = 1.f / (1.f + expf(-sm.instr[bb][off + 129]));
        float s0 = sm.instr[bb][off + 130], s1 = sm.instr[bb][off + 131], s2 = sm.instr[bb][off + 132];
        float smx = fmaxf(s0, fmaxf(s1, s2));
        float e0 = expf(s0 - smx), e1 = expf(s1 - smx), e2 = expf(s2 - smx);
        float esm = e0 + e1 + e2; s0 = e0/esm; s1 = e1/esm; s2 = e2/esm;
        float spx = sm.instr[bb][off + 133];
        float tt = ((spx > 20.f) ? spx : log1pf(expf(spx))) + 1.0f;
        {
          int n = lt & 127, h = lt >> 7;
          float p = 0.f;
          #pragma unroll 8
          for (int q = 0; q < 64; ++q) {
            int m = h * 64 + q;
            p += sm.Mem[bb][n][m] * sm.u.d.invn[bb][m] * sm.instr[bb][off + m];
          }
          sm.u.d.red[bb][lt] = p;
        }
        __syncthreads();
        float simv = -1e30f, evv = 0.f;
        if (lt < 128) simv = (sm.u.d.red[bb][lt] + sm.u.d.red[bb][lt+128]) * invk * beta;
        float mx = red_max_half(simv, scal4, tid);
        if (lt < 128) evv = expf(simv - mx);
        float es = red_sum_half(evv, scal4, tid);
        if (lt < 128) {
          float wcv = evv / es;
          float wold = (hd < RR) ? sm.rw[bb][hd][lt] : sm.ww[bb][lt];
          sm.u.d.wi[bb][lt] = gg * wcv + (1.f - gg) * wold;
        }
        __syncthreads();
        float pv = 0.f;
        if (lt < 128) {
          float wsv = s0 * sm.u.d.wi[bb][(lt + 127) & 127] + s1 * sm.u.d.wi[bb][lt]
                    + s2 * sm.u.d.wi[bb][(lt + 1) & 127];
          pv = powf(wsv, tt);
        }
        float ps = red_sum_half(pv, scal4, tid);
        if (lt < 128) {
          float wn = pv / (ps + 1e-12f);
          if (hd < RR) sm.rw[bb][hd][lt] = wn; else sm.ww[bb][lt] = wn;
        }
        __syncthreads();
      }
      for (int e = lt; e < NN * MMM; e += 256) {
        int n = e >> 7, m = e & 127;
        float w = sm.ww[bb][n];
        sm.Mem[bb][n][m] = sm.Mem[bb][n][m] * (1.f - w * sm.instr[bb][670 + m])
                         + w * sm.instr[bb][798 + m];
      }
      __syncthreads();
      for (int e = lt; e < RR * MMM; e += 256) {
        int r = e >> 7, m = e & 127;
        float acc = 0.f;
        #pragma unroll 8
        for (int n = 0; n < NN; ++n) acc += sm.Mem[bb][n][m] * sm.rw[bb][r][n];
        sm.rv[bb][e] = acc;
      }
    }
    __syncthreads();   // rv ready for next step's phase B
  }
}

// ---------------- launch ----------------
extern "C" void kernel_launch(void* const* d_in, const int* in_sizes, int n_in,
                              void* d_out, int out_size, void* d_ws, size_t ws_size,
                              hipStream_t stream) {
  const float* x  = (const float*)d_in[0];
  const float* Wc = (const float*)d_in[1];
  const float* bc = (const float*)d_in[2];
  const float* Wk = (const float*)d_in[3];
  const float* bk = (const float*)d_in[4];
  float* out = (float*)d_out;

  char* ws = (char*)d_ws;
  float* Wkp = (float*)ws;                                   // 512*928*4 = 1,900,544 B
  float* bkp = (float*)(ws + (size_t)512 * NOUTP * 4);       // 928*4 B

  pack_wk<<<dim3(512), dim3(256), 0, stream>>>(Wk, bk, Wkp, bkp);
  pre_mm<<<dim3(1024), dim3(256), 0, stream>>>(x, Wc, bc, out);
  ntm2<<<dim3(B_ / 2), dim3(NTHR), 0, stream>>>(Wc, Wkp, bkp, out);
}

// Round 4
// 4531.800 us; speedup vs baseline: 1.7069x; 1.7069x over previous
//
#include <hip/hip_runtime.h>
#include <math.h>

// ---------------- problem constants ----------------
#define B_    128
#define T_    64
#define INX   512
#define CTRL  512
#define NN    128
#define MMM   128
#define RR    4
#define LLh   134   // per-read-head instr length (3+MM+S)
#define NOUT  926
#define NTHR  512   // 2 batches/WG, 256 threads per batch-half

// Mem row stride 129: bank(129n+m)%32 = (n+m)%32 -> conflict-free both axes
#define MSTR  129

struct __align__(16) SM2 {
  float Mem[2][NN][MSTR];     // 132,096 B (persistent per-WG)
  float rw[2][RR][NN];        //   4,096 B
  float ww[2][NN];            //   1,024 B
  float instr[2][928];        //   7,424 B
  float rv[2][512];           //   4,096 B
  union {                     //   4,160 B (out_s dead by phase D)
    float out_s[2][512];
    struct { float red[2][256]; float wi[2][NN]; float invn[2][MMM]; float scal[2][8]; } d;
  } u;
};  // 152,896 B -> 1 WG/CU, 64 WGs on 256 CUs (8 per XCD; weights L2-resident)

// ---------------- per-half (256-thread) reductions; all 512 threads call together ----
__device__ __forceinline__ float red_sum_half(float v, volatile float* scal4, int tid) {
  #pragma unroll
  for (int m = 32; m >= 1; m >>= 1) v += __shfl_xor(v, m);
  if ((tid & 63) == 0) scal4[(tid >> 6) & 3] = v;
  __syncthreads();
  float r = scal4[0] + scal4[1] + scal4[2] + scal4[3];
  __syncthreads();
  return r;
}
__device__ __forceinline__ float red_max_half(float v, volatile float* scal4, int tid) {
  #pragma unroll
  for (int m = 32; m >= 1; m >>= 1) v = fmaxf(v, __shfl_xor(v, m));
  if ((tid & 63) == 0) scal4[(tid >> 6) & 3] = v;
  __syncthreads();
  float r = fmaxf(fmaxf(scal4[0], scal4[1]), fmaxf(scal4[2], scal4[3]));
  __syncthreads();
  return r;
}

// ---------------- precompute: d_out = X(8192x512) @ Wc[0:512,:] + bc ----------------
__global__ __launch_bounds__(256) void pre_mm(const float* __restrict__ X,
                                              const float* __restrict__ Wc,
                                              const float* __restrict__ bc,
                                              float* __restrict__ out) {
  __shared__ float Xs[16][68];
  __shared__ float Ws[16][64];
  const int wg = blockIdx.x;
  const int r0 = (wg >> 3) * 64, c0 = (wg & 7) * 64;
  const int tid = threadIdx.x;
  const int ti = tid >> 4, tj = tid & 15;
  float acc[4][4] = {};
  for (int kk = 0; kk < 512; kk += 16) {
    __syncthreads();
    for (int e = tid; e < 1024; e += 256) {
      int i = e >> 4, k = e & 15;
      Xs[k][i] = X[(size_t)(r0 + i) * 512 + kk + k];
    }
    for (int e = tid; e < 1024; e += 256) {
      int k = e >> 6, j = e & 63;
      Ws[k][j] = Wc[(size_t)(kk + k) * CTRL + c0 + j];
    }
    __syncthreads();
    #pragma unroll
    for (int k = 0; k < 16; ++k) {
      float a0 = Xs[k][ti*4+0], a1 = Xs[k][ti*4+1], a2 = Xs[k][ti*4+2], a3 = Xs[k][ti*4+3];
      float b0 = Ws[k][tj*4+0], b1 = Ws[k][tj*4+1], b2 = Ws[k][tj*4+2], b3 = Ws[k][tj*4+3];
      acc[0][0]+=a0*b0; acc[0][1]+=a0*b1; acc[0][2]+=a0*b2; acc[0][3]+=a0*b3;
      acc[1][0]+=a1*b0; acc[1][1]+=a1*b1; acc[1][2]+=a1*b2; acc[1][3]+=a1*b3;
      acc[2][0]+=a2*b0; acc[2][1]+=a2*b1; acc[2][2]+=a2*b2; acc[2][3]+=a2*b3;
      acc[3][0]+=a3*b0; acc[3][1]+=a3*b1; acc[3][2]+=a3*b2; acc[3][3]+=a3*b3;
    }
  }
  #pragma unroll
  for (int i = 0; i < 4; ++i) {
    size_t o = (size_t)(r0 + ti*4 + i) * 512 + c0 + tj*4;
    float4 v = { acc[i][0] + bc[c0+tj*4+0], acc[i][1] + bc[c0+tj*4+1],
                 acc[i][2] + bc[c0+tj*4+2], acc[i][3] + bc[c0+tj*4+3] };
    *(float4*)&out[o] = v;
  }
}

// ---------------- persistent per-batch-pair kernel: NO grid sync ----------------
__global__ __launch_bounds__(512) void ntm2(const float* __restrict__ Wc,
                                            const float* __restrict__ Wk,
                                            const float* __restrict__ bk,
                                            float* __restrict__ out) {
  __shared__ SM2 sm;
  const int wg = blockIdx.x, tid = threadIdx.x;
  const int b0 = wg * 2;
  const int lt = tid & 255, bb = tid >> 8;   // half-local id / batch within WG
  const int j  = tid;                        // column id for phase B

  // ---- init state ----
  for (int e = tid; e < 2 * NN * MMM; e += NTHR) {
    int bl = e >> 14, n = (e >> 7) & 127;
    sm.Mem[bl][n][e & 127] = (n == NN / 2) ? 1.0f : 0.0f;
  }
  for (int e = tid; e < 2 * RR * NN; e += NTHR) ((float*)sm.rw)[e] = 0.0f;
  for (int e = tid; e < 2 * NN;      e += NTHR) ((float*)sm.ww)[e] = 0.0f;
  for (int e = tid; e < 2 * 512;     e += NTHR) ((float*)sm.rv)[e] = 0.0f;
  __syncthreads();

  for (int t = 0; t < T_; ++t) {
    // ===== phase B: out[b][t][j] = tanh(pre + rv_b @ Wc2[:,j]) =====
    // thread j owns column j for BOTH batches -> each weight load feeds 2 FMA
    // (identical to round-2 proven version)
    {
      float a0 = 0.f, a1 = 0.f;
      const float* wp = Wc + (size_t)INX * CTRL + j;
      for (int k4 = 0; k4 < 512; k4 += 4) {
        float4 r0 = *(const float4*)&sm.rv[0][k4];
        float4 r1 = *(const float4*)&sm.rv[1][k4];
        float w0 = wp[(size_t)(k4+0)*CTRL];
        float w1 = wp[(size_t)(k4+1)*CTRL];
        float w2 = wp[(size_t)(k4+2)*CTRL];
        float w3 = wp[(size_t)(k4+3)*CTRL];
        a0 += r0.x*w0 + r0.y*w1 + r0.z*w2 + r0.w*w3;
        a1 += r1.x*w0 + r1.y*w1 + r1.z*w2 + r1.w*w3;
      }
      size_t o0 = ((size_t)(b0+0)*T_ + t)*CTRL + j;
      size_t o1 = ((size_t)(b0+1)*T_ + t)*CTRL + j;
      float v0 = tanhf(out[o0] + a0);
      float v1 = tanhf(out[o1] + a1);
      out[o0] = v0; out[o1] = v1;
      sm.u.out_s[0][j] = v0; sm.u.out_s[1][j] = v1;
    }
    __syncthreads();

    // ===== phase C: instr = out_t @ Wk + bk, float2 column-pairs =====
    // thread j < 464 owns cols (2j, 2j+1): 512 float2 loads -> 4 FMA each.
    // Wk row stride 926 floats (even) -> (k*926 + 2j)*4B is 8B-aligned.
    if (j < 463 || (j == 463)) { }  // (no-op; keep structure flat)
    {
      float a00 = 0.f, a01 = 0.f, a10 = 0.f, a11 = 0.f;
      if (j < 464) {
        const float* wp = Wk + 2 * j;
        for (int k4 = 0; k4 < 512; k4 += 4) {
          float4 o0 = *(const float4*)&sm.u.out_s[0][k4];
          float4 o1 = *(const float4*)&sm.u.out_s[1][k4];
          float2 w0 = *(const float2*)&wp[(size_t)(k4+0)*NOUT];
          float2 w1 = *(const float2*)&wp[(size_t)(k4+1)*NOUT];
          float2 w2 = *(const float2*)&wp[(size_t)(k4+2)*NOUT];
          float2 w3 = *(const float2*)&wp[(size_t)(k4+3)*NOUT];
          a00 += o0.x*w0.x + o0.y*w1.x + o0.z*w2.x + o0.w*w3.x;
          a01 += o0.x*w0.y + o0.y*w1.y + o0.z*w2.y + o0.w*w3.y;
          a10 += o1.x*w0.x + o1.y*w1.x + o1.z*w2.x + o1.w*w3.x;
          a11 += o1.x*w0.y + o1.y*w1.y + o1.z*w2.y + o1.w*w3.y;
        }
      }
      // no sync needed between B's out_s writes and here beyond the one above;
      // write results
      if (j < 464) {
        float2 bias = { bk[2*j], bk[2*j + 1] };
        float2 r0 = { a00 + bias.x, a01 + bias.y };
        float2 r1 = { a10 + bias.x, a11 + bias.y };
        *(float2*)&sm.instr[0][2*j] = r0;
        *(float2*)&sm.instr[1][2*j] = r1;
      }
    }
    __syncthreads();

    // ===== phase D: heads + Mem update + rv (halves: 256 threads per batch) =====
    {
      volatile float* scal4 = sm.u.d.scal[bb];
      // column inv-norms over n (reference: _l2n(Mem, axis=1))
      {
        int m = lt & 127, h = lt >> 7;
        float p = 0.f;
        #pragma unroll 8
        for (int q = 0; q < 64; ++q) { float v = sm.Mem[bb][h*64+q][m]; p += v*v; }
        sm.u.d.red[bb][lt] = p;
      }
      __syncthreads();
      if (lt < 128) sm.u.d.invn[bb][lt] =
          rsqrtf(fmaxf(sm.u.d.red[bb][lt] + sm.u.d.red[bb][lt+128], 1e-12f));
      __syncthreads();

      for (int hd = 0; hd < 5; ++hd) {
        const int off = (hd < RR) ? hd * LLh : RR * LLh;
        float kv = (lt < 128) ? sm.instr[bb][off + lt] : 0.f;
        float kn2 = red_sum_half(kv * kv, scal4, tid);
        float invk = rsqrtf(fmaxf(kn2, 1e-12f));
        float beta = expf(sm.instr[bb][off + 128]);
        float gg = 1.f / (1.f + expf(-sm.instr[bb][off + 129]));
        float s0 = sm.instr[bb][off + 130], s1 = sm.instr[bb][off + 131], s2 = sm.instr[bb][off + 132];
        float smx = fmaxf(s0, fmaxf(s1, s2));
        float e0 = expf(s0 - smx), e1 = expf(s1 - smx), e2 = expf(s2 - smx);
        float esm = e0 + e1 + e2; s0 = e0/esm; s1 = e1/esm; s2 = e2/esm;
        float spx = sm.instr[bb][off + 133];
        float tt = ((spx > 20.f) ? spx : log1pf(expf(spx))) + 1.0f;
        // sim[n] = (sum_m Mem[n][m]*invn[m]*k[m]) * invk * beta
        {
          int n = lt & 127, h = lt >> 7;
          float p = 0.f;
          #pragma unroll 8
          for (int q = 0; q < 64; ++q) {
            int m = h * 64 + q;
            p += sm.Mem[bb][n][m] * sm.u.d.invn[bb][m] * sm.instr[bb][off + m];
          }
          sm.u.d.red[bb][lt] = p;
        }
        __syncthreads();
        float simv = -1e30f, evv = 0.f;
        if (lt < 128) simv = (sm.u.d.red[bb][lt] + sm.u.d.red[bb][lt+128]) * invk * beta;
        float mx = red_max_half(simv, scal4, tid);
        if (lt < 128) evv = expf(simv - mx);
        float es = red_sum_half(evv, scal4, tid);
        if (lt < 128) {
          float wcv = evv / es;
          float wold = (hd < RR) ? sm.rw[bb][hd][lt] : sm.ww[bb][lt];
          sm.u.d.wi[bb][lt] = gg * wcv + (1.f - gg) * wold;
        }
        __syncthreads();
        float pv = 0.f;
        if (lt < 128) {
          float wsv = s0 * sm.u.d.wi[bb][(lt + 127) & 127] + s1 * sm.u.d.wi[bb][lt]
                    + s2 * sm.u.d.wi[bb][(lt + 1) & 127];
          pv = powf(wsv, tt);
        }
        float ps = red_sum_half(pv, scal4, tid);
        if (lt < 128) {
          float wn = pv / (ps + 1e-12f);
          if (hd < RR) sm.rw[bb][hd][lt] = wn; else sm.ww[bb][lt] = wn;
        }
        __syncthreads();
      }
      // Mem = Mem*(1 - ww[n]*e[m]) + ww[n]*a[m]
      for (int e = lt; e < NN * MMM; e += 256) {
        int n = e >> 7, m = e & 127;
        float w = sm.ww[bb][n];
        sm.Mem[bb][n][m] = sm.Mem[bb][n][m] * (1.f - w * sm.instr[bb][670 + m])
                         + w * sm.instr[bb][798 + m];
      }
      __syncthreads();
      // rv[r*128+m] = sum_n Mem[n][m] * rw[r][n]
      for (int e = lt; e < RR * MMM; e += 256) {
        int r = e >> 7, m = e & 127;
        float acc = 0.f;
        #pragma unroll 8
        for (int n = 0; n < NN; ++n) acc += sm.Mem[bb][n][m] * sm.rw[bb][r][n];
        sm.rv[bb][e] = acc;
      }
    }
    __syncthreads();   // rv ready for next step's phase B
  }
}

// ---------------- launch ----------------
extern "C" void kernel_launch(void* const* d_in, const int* in_sizes, int n_in,
                              void* d_out, int out_size, void* d_ws, size_t ws_size,
                              hipStream_t stream) {
  const float* x  = (const float*)d_in[0];
  const float* Wc = (const float*)d_in[1];
  const float* bc = (const float*)d_in[2];
  const float* Wk = (const float*)d_in[3];
  const float* bk = (const float*)d_in[4];
  float* out = (float*)d_out;

  pre_mm<<<dim3(1024), dim3(256), 0, stream>>>(x, Wc, bc, out);
  ntm2<<<dim3(B_ / 2), dim3(NTHR), 0, stream>>>(Wc, Wk, bk, out);
}

// Round 7
// 3187.814 us; speedup vs baseline: 2.4265x; 1.4216x over previous
//
#include <hip/hip_runtime.h>
#include <math.h>

// ---------------- problem constants ----------------
#define B_    128
#define T_    64
#define INX   512
#define CTRL  512
#define NN    128
#define MMM   128
#define RR    4
#define LLh   134   // per-read-head instr length (3+MM+S)
#define NOUT  926
#define NTHR  512   // 2 batches/WG, 256 threads per batch-half

// Mem row stride 129: bank(129n+m)%32 = (n+m)%32 -> conflict-free both axes
#define MSTR  129

struct __align__(16) SM2 {
  float Mem[2][NN][MSTR];     // 132,096 B (persistent per-WG)
  float rw[2][RR][NN];        //   4,096 B
  float ww[2][NN];            //   1,024 B
  float instr[2][928];        //   7,424 B
  float rv[2][512];           //   4,096 B
  union {                     //   4,096 B (out_s dead by phase D)
    float out_s[2][512];
    struct { float red[2][256]; float invn[2][MMM]; } d;   // 3,072 B
  } u;
};  // 152,832 B -> 1 WG/CU, 64 WGs on 256 CUs (weights L2-resident per XCD)

// ---------------- 64-lane wave reductions (no barriers) ----------------
__device__ __forceinline__ float wsum64(float v) {
  #pragma unroll
  for (int m = 32; m >= 1; m >>= 1) v += __shfl_xor(v, m);
  return v;
}
__device__ __forceinline__ float wmax64(float v) {
  #pragma unroll
  for (int m = 32; m >= 1; m >>= 1) v = fmaxf(v, __shfl_xor(v, m));
  return v;
}

// ---------------- precompute: d_out = X(8192x512) @ Wc[0:512,:] + bc ----------------
__global__ __launch_bounds__(256) void pre_mm(const float* __restrict__ X,
                                              const float* __restrict__ Wc,
                                              const float* __restrict__ bc,
                                              float* __restrict__ out) {
  __shared__ float Xs[16][68];
  __shared__ float Ws[16][64];
  const int wg = blockIdx.x;
  const int r0 = (wg >> 3) * 64, c0 = (wg & 7) * 64;
  const int tid = threadIdx.x;
  const int ti = tid >> 4, tj = tid & 15;
  float acc[4][4] = {};
  for (int kk = 0; kk < 512; kk += 16) {
    __syncthreads();
    for (int e = tid; e < 1024; e += 256) {
      int i = e >> 4, k = e & 15;
      Xs[k][i] = X[(size_t)(r0 + i) * 512 + kk + k];
    }
    for (int e = tid; e < 1024; e += 256) {
      int k = e >> 6, j = e & 63;
      Ws[k][j] = Wc[(size_t)(kk + k) * CTRL + c0 + j];
    }
    __syncthreads();
    #pragma unroll
    for (int k = 0; k < 16; ++k) {
      float a0 = Xs[k][ti*4+0], a1 = Xs[k][ti*4+1], a2 = Xs[k][ti*4+2], a3 = Xs[k][ti*4+3];
      float b0 = Ws[k][tj*4+0], b1 = Ws[k][tj*4+1], b2 = Ws[k][tj*4+2], b3 = Ws[k][tj*4+3];
      acc[0][0]+=a0*b0; acc[0][1]+=a0*b1; acc[0][2]+=a0*b2; acc[0][3]+=a0*b3;
      acc[1][0]+=a1*b0; acc[1][1]+=a1*b1; acc[1][2]+=a1*b2; acc[1][3]+=a1*b3;
      acc[2][0]+=a2*b0; acc[2][1]+=a2*b1; acc[2][2]+=a2*b2; acc[2][3]+=a2*b3;
      acc[3][0]+=a3*b0; acc[3][1]+=a3*b1; acc[3][2]+=a3*b2; acc[3][3]+=a3*b3;
    }
  }
  #pragma unroll
  for (int i = 0; i < 4; ++i) {
    size_t o = (size_t)(r0 + ti*4 + i) * 512 + c0 + tj*4;
    float4 v = { acc[i][0] + bc[c0+tj*4+0], acc[i][1] + bc[c0+tj*4+1],
                 acc[i][2] + bc[c0+tj*4+2], acc[i][3] + bc[c0+tj*4+3] };
    *(float4*)&out[o] = v;
  }
}

// ---------------- one head task on one wave (64 lanes, no barriers, no LDS scratch) --
// tau in 0..9: batch = tau/5, head = tau%5. Reads pre-update Mem/invn/instr/w_old,
// writes rw[b][hd] (hd<4) or ww[b] (hd==4). The +-1 ring shift of wi is done with
// __shfl (register exchange) -- NO same-wave LDS write->read (that was UB, round 6).
__device__ __forceinline__ void do_head(SM2& sm, int tau, int lane) {
  const int b  = tau / 5;
  const int hd = tau - 5 * b;
  const int off = (hd < RR) ? hd * LLh : RR * LLh;
  const float* ins = sm.instr[b];
  const int n0 = lane, n1 = lane + 64;

  // key inv-norm over m
  float k0 = ins[off + n0], k1 = ins[off + n1];
  float invk = rsqrtf(fmaxf(wsum64(k0 * k0 + k1 * k1), 1e-12f));
  // scalar head params (wave-uniform LDS broadcasts)
  float beta = expf(ins[off + 128]);
  float gg = 1.f / (1.f + expf(-ins[off + 129]));
  float s0 = ins[off + 130], s1 = ins[off + 131], s2 = ins[off + 132];
  float smx = fmaxf(s0, fmaxf(s1, s2));
  float e0 = expf(s0 - smx), e1 = expf(s1 - smx), e2 = expf(s2 - smx);
  float esm = e0 + e1 + e2; s0 = e0 / esm; s1 = e1 / esm; s2 = e2 / esm;
  float spx = ins[off + 133];
  float tt = ((spx > 20.f) ? spx : log1pf(expf(spx))) + 1.0f;

  // sim[n] = (sum_m Mem[n][m]*invn[m]*k[m]) * invk * beta  (lane owns n0, n1)
  float p0 = 0.f, p1 = 0.f;
  #pragma unroll 4
  for (int m = 0; m < 128; ++m) {
    float km = sm.u.d.invn[b][m] * ins[off + m];
    p0 += sm.Mem[b][n0][m] * km;
    p1 += sm.Mem[b][n1][m] * km;
  }
  float sim0 = p0 * invk * beta, sim1 = p1 * invk * beta;
  float mx = wmax64(fmaxf(sim0, sim1));
  float ev0 = expf(sim0 - mx), ev1 = expf(sim1 - mx);
  float es = wsum64(ev0 + ev1);
  float wold0 = (hd < RR) ? sm.rw[b][hd][n0] : sm.ww[b][n0];
  float wold1 = (hd < RR) ? sm.rw[b][hd][n1] : sm.ww[b][n1];
  float wi0 = gg * (ev0 / es) + (1.f - gg) * wold0;   // wi[lane]
  float wi1 = gg * (ev1 / es) + (1.f - gg) * wold1;   // wi[lane+64]

  // ring shift wi[n-1], wi[n+1] mod 128 via register shuffles:
  // prev: srcLane = lane-1 (mod 64); half-swap at lane 0
  int ls = (lane + 63) & 63;
  float A0 = __shfl(wi0, ls), A1 = __shfl(wi1, ls);
  float wprev0 = (lane == 0) ? A1 : A0;   // wi[(n0+127)&127]
  float wprev1 = (lane == 0) ? A0 : A1;   // wi[(n1+127)&127]
  // next: srcLane = lane+1 (mod 64); half-swap at lane 63
  int ln = (lane + 1) & 63;
  float B0 = __shfl(wi0, ln), B1 = __shfl(wi1, ln);
  float wnext0 = (lane == 63) ? B1 : B0;  // wi[(n0+1)&127]
  float wnext1 = (lane == 63) ? B0 : B1;  // wi[(n1+1)&127]

  float ws0 = s0 * wprev0 + s1 * wi0 + s2 * wnext0;
  float ws1 = s0 * wprev1 + s1 * wi1 + s2 * wnext1;
  float pv0 = powf(ws0, tt), pv1 = powf(ws1, tt);
  float inv = 1.f / (wsum64(pv0 + pv1) + 1e-12f);
  if (hd < RR) { sm.rw[b][hd][n0] = pv0 * inv; sm.rw[b][hd][n1] = pv1 * inv; }
  else         { sm.ww[b][n0]     = pv0 * inv; sm.ww[b][n1]     = pv1 * inv; }
}

// ---------------- persistent per-batch-pair kernel: NO grid sync ----------------
__global__ __launch_bounds__(512) void ntm2(const float* __restrict__ Wc,
                                            const float* __restrict__ Wk,
                                            const float* __restrict__ bk,
                                            float* __restrict__ out) {
  __shared__ SM2 sm;
  const int wg = blockIdx.x, tid = threadIdx.x;
  const int b0 = wg * 2;
  const int lt = tid & 255, bb = tid >> 8;   // half-local id / batch within WG
  const int j  = tid;                        // column id for GEMV phases
  const int wv = tid >> 6, lane = tid & 63;  // wave id / lane for phase D

  // ---- init state ----
  for (int e = tid; e < 2 * NN * MMM; e += NTHR) {
    int bl = e >> 14, n = (e >> 7) & 127;
    sm.Mem[bl][n][e & 127] = (n == NN / 2) ? 1.0f : 0.0f;
  }
  for (int e = tid; e < 2 * RR * NN; e += NTHR) ((float*)sm.rw)[e] = 0.0f;
  for (int e = tid; e < 2 * NN;      e += NTHR) ((float*)sm.ww)[e] = 0.0f;
  for (int e = tid; e < 2 * 512;     e += NTHR) ((float*)sm.rv)[e] = 0.0f;
  __syncthreads();

  for (int t = 0; t < T_; ++t) {
    // ===== phase B: out[b][t][j] = tanh(pre + rv_b @ Wc2[:,j]) =====
    // round-2 access pattern, unrolled 8-deep (8 scalar loads in flight)
    {
      float a0 = 0.f, a1 = 0.f;
      const float* wp = Wc + (size_t)INX * CTRL + j;
      for (int k8 = 0; k8 < 512; k8 += 8) {
        float w0 = wp[(size_t)(k8+0)*CTRL];
        float w1 = wp[(size_t)(k8+1)*CTRL];
        float w2 = wp[(size_t)(k8+2)*CTRL];
        float w3 = wp[(size_t)(k8+3)*CTRL];
        float w4 = wp[(size_t)(k8+4)*CTRL];
        float w5 = wp[(size_t)(k8+5)*CTRL];
        float w6 = wp[(size_t)(k8+6)*CTRL];
        float w7 = wp[(size_t)(k8+7)*CTRL];
        float4 r0a = *(const float4*)&sm.rv[0][k8];
        float4 r0b = *(const float4*)&sm.rv[0][k8+4];
        float4 r1a = *(const float4*)&sm.rv[1][k8];
        float4 r1b = *(const float4*)&sm.rv[1][k8+4];
        a0 += r0a.x*w0 + r0a.y*w1 + r0a.z*w2 + r0a.w*w3
            + r0b.x*w4 + r0b.y*w5 + r0b.z*w6 + r0b.w*w7;
        a1 += r1a.x*w0 + r1a.y*w1 + r1a.z*w2 + r1a.w*w3
            + r1b.x*w4 + r1b.y*w5 + r1b.z*w6 + r1b.w*w7;
      }
      size_t o0 = ((size_t)(b0+0)*T_ + t)*CTRL + j;
      size_t o1 = ((size_t)(b0+1)*T_ + t)*CTRL + j;
      float v0 = tanhf(out[o0] + a0);
      float v1 = tanhf(out[o1] + a1);
      out[o0] = v0; out[o1] = v1;
      sm.u.out_s[0][j] = v0; sm.u.out_s[1][j] = v1;
    }
    __syncthreads();

    // ===== phase C: instr = out_t @ Wk + bk (round-2 proven version) =====
    // thread j owns cols j and j+512 (if <926): 2 scalar streams, 8 loads in flight
    {
      const int c1 = (j < NOUT - 512) ? j + 512 : j;   // clamp to stay in-bounds
      float a00 = 0.f, a10 = 0.f, a01 = 0.f, a11 = 0.f;
      const float* wp0 = Wk + j;
      const float* wp1 = Wk + c1;
      for (int k4 = 0; k4 < 512; k4 += 4) {
        float4 o0 = *(const float4*)&sm.u.out_s[0][k4];
        float4 o1 = *(const float4*)&sm.u.out_s[1][k4];
        #pragma unroll
        for (int i = 0; i < 4; ++i) {
          float w0 = wp0[(size_t)(k4+i)*NOUT];
          float w1 = wp1[(size_t)(k4+i)*NOUT];
          float e0 = (i==0)? o0.x : (i==1)? o0.y : (i==2)? o0.z : o0.w;
          float e1 = (i==0)? o1.x : (i==1)? o1.y : (i==2)? o1.z : o1.w;
          a00 += e0 * w0; a01 += e0 * w1;
          a10 += e1 * w0; a11 += e1 * w1;
        }
      }
      sm.instr[0][j] = a00 + bk[j];
      sm.instr[1][j] = a10 + bk[j];
      if (j < NOUT - 512) {
        sm.instr[0][j+512] = a01 + bk[j+512];
        sm.instr[1][j+512] = a11 + bk[j+512];
      }
    }
    __syncthreads();

    // ===== phase D: column norms -> 10 wave-parallel head tasks -> Mem -> rv =====
    {
      // 0) column inv-norms over n (reference: _l2n(Mem, axis=1))
      {
        int m = lt & 127, h = lt >> 7;
        float p = 0.f;
        #pragma unroll 8
        for (int q = 0; q < 64; ++q) { float v = sm.Mem[bb][h*64+q][m]; p += v*v; }
        sm.u.d.red[bb][lt] = p;
      }
      __syncthreads();
      if (lt < 128) sm.u.d.invn[bb][lt] =
          rsqrtf(fmaxf(sm.u.d.red[bb][lt] + sm.u.d.red[bb][lt+128], 1e-12f));
      __syncthreads();

      // 1) heads: pass 0 = tasks 0..7 (one per wave); pass 1 = tasks 8,9 (waves 0,1)
      do_head(sm, wv, lane);
      if (wv < 2) do_head(sm, 8 + wv, lane);
      __syncthreads();

      // 2) Mem = Mem*(1 - ww[n]*e[m]) + ww[n]*a[m]
      for (int e = lt; e < NN * MMM; e += 256) {
        int n = e >> 7, m = e & 127;
        float w = sm.ww[bb][n];
        sm.Mem[bb][n][m] = sm.Mem[bb][n][m] * (1.f - w * sm.instr[bb][670 + m])
                         + w * sm.instr[bb][798 + m];
      }
      __syncthreads();

      // 3) rv[r*128+m] = sum_n Mem[n][m] * rw[r][n]
      for (int e = lt; e < RR * MMM; e += 256) {
        int r = e >> 7, m = e & 127;
        float acc = 0.f;
        #pragma unroll 8
        for (int n = 0; n < NN; ++n) acc += sm.Mem[bb][n][m] * sm.rw[bb][r][n];
        sm.rv[bb][e] = acc;
      }
    }
    __syncthreads();   // rv ready for next step's phase B
  }
}

// ---------------- launch ----------------
extern "C" void kernel_launch(void* const* d_in, const int* in_sizes, int n_in,
                              void* d_out, int out_size, void* d_ws, size_t ws_size,
                              hipStream_t stream) {
  const float* x  = (const float*)d_in[0];
  const float* Wc = (const float*)d_in[1];
  const float* bc = (const float*)d_in[2];
  const float* Wk = (const float*)d_in[3];
  const float* bk = (const float*)d_in[4];
  float* out = (float*)d_out;

  pre_mm<<<dim3(1024), dim3(256), 0, stream>>>(x, Wc, bc, out);
  ntm2<<<dim3(B_ / 2), dim3(NTHR), 0, stream>>>(Wc, Wk, bk, out);
}